// Round 3
// baseline (330.316 us; speedup 1.0000x reference)
//
#include <hip/hip_runtime.h>
#include <hip/hip_bf16.h>

typedef unsigned short u16;
typedef unsigned int   u32;
typedef __attribute__((ext_vector_type(8))) short bf16x8;
typedef __attribute__((ext_vector_type(4))) short bf16x4;
typedef __attribute__((ext_vector_type(4))) float f32x4;
typedef __attribute__((ext_vector_type(4))) unsigned short u16x4;

__device__ __forceinline__ u16 f32_to_bf16bits(float f) {
    u32 x = __float_as_uint(f);
    u32 r = (x + 0x7fffu + ((x >> 16) & 1u)) >> 16;   // RNE
    return (u16)r;
}
__device__ __forceinline__ float bf16bits_to_f32(u16 u) {
    return __uint_as_float(((u32)u) << 16);
}
__device__ __forceinline__ u32 cvt_pk_bf16(float lo, float hi) {
    u32 r;
    asm("v_cvt_pk_bf16_f32 %0, %1, %2" : "=v"(r) : "v"(lo), "v"(hi));
    return r;
}

// async global->LDS, 16B per lane. LDS dest is wave-uniform base + lane*16.
__device__ __forceinline__ void async_copy16(void* lds, const void* g) {
    __builtin_amdgcn_global_load_lds(
        (__attribute__((address_space(1))) void*)(g),
        (__attribute__((address_space(3))) void*)(lds), 16, 0, 0);
}

// ---------------------------------------------------------------- convert x
__global__ void convert_f32_bf16(const float* __restrict__ src, u16* __restrict__ dst, int n4) {
    const int i = blockIdx.x * 256 + threadIdx.x;
    if (i >= n4) return;
    const float4 v = ((const float4*)src)[i];
    u16x4 o = { f32_to_bf16bits(v.x), f32_to_bf16bits(v.y),
                f32_to_bf16bits(v.z), f32_to_bf16bits(v.w) };
    ((u16x4*)dst)[i] = o;
}

// ------------------------------------------- weight transpose fp32(K,N)->bf16(N,K)
// tile: 32 k-rows x 128 n-cols; coalesced f32 reads, packed u16x2 writes.
__global__ void transpose_wT(const float* __restrict__ src, u16* __restrict__ dst,
                             int N, int dstStride) {
    __shared__ float tile[32][129];
    const int n0 = blockIdx.x * 128, k0 = blockIdx.y * 32;
    const int tx = threadIdx.x, ty = threadIdx.y;      // (32, 8)
#pragma unroll
    for (int j = 0; j < 4; ++j)
#pragma unroll
        for (int i = 0; i < 4; ++i)
            tile[ty + 8*j][tx + 32*i] = src[(size_t)(k0 + ty + 8*j) * N + n0 + tx + 32*i];
    __syncthreads();
    const int tid = ty * 32 + tx;
    const int c = tid & 15, nl0 = tid >> 4;
#pragma unroll
    for (int s = 0; s < 8; ++s) {
        const int nl = nl0 + s * 16;
        const u32 pk = (u32)f32_to_bf16bits(tile[2*c][nl])
                     | ((u32)f32_to_bf16bits(tile[2*c + 1][nl]) << 16);
        *(u32*)&dst[(size_t)(n0 + nl) * dstStride + k0 + 2*c] = pk;
    }
}

// ------------------------------------------- V transpose bf16 (s,dcol)->(dcol,s)
__global__ void transpose_v(const u16* __restrict__ qkv, u16* __restrict__ vT) {
    __shared__ u16 tile[32][34];
    const int s0 = blockIdx.x * 32, n0 = blockIdx.y * 32;
    const int tx = threadIdx.x, ty = threadIdx.y;
#pragma unroll
    for (int i = 0; i < 4; ++i)
        tile[ty + i*8][tx] = qkv[(size_t)(s0 + ty + i*8) * 6144 + 5120 + n0 + tx];
    __syncthreads();
#pragma unroll
    for (int i = 0; i < 4; ++i)
        vT[(size_t)(n0 + ty + i*8) * 2048 + s0 + tx] = tile[tx][ty + i*8];
}

// ---------------------------------------------------------------- RoPE in place
__global__ void rope_kernel(u32* __restrict__ qkv, const float* __restrict__ cosp,
                            const float* __restrict__ sinp) {
    const int s = blockIdx.x;
    const int h = blockIdx.y * 4 + (threadIdx.x >> 6);
    const int p = threadIdx.x & 63;
    const size_t off = ((size_t)s * 6144 + h * 128) >> 1;
    const u32 packed = qkv[off + p];
    const float c  = cosp[s*64 + p], sn = sinp[s*64 + p];
    const float t1 = bf16bits_to_f32((u16)(packed & 0xffffu));
    const float t2 = bf16bits_to_f32((u16)(packed >> 16));
    const float o1 = t1 * c - t2 * sn;
    const float o2 = t1 * sn + t2 * c;
    qkv[off + p] = (u32)f32_to_bf16bits(o1) | ((u32)f32_to_bf16bits(o2) << 16);
}

// ---------------------------------------------------------------- ring GEMM
// C[M,N] = A[M,K] * B[N,K]^T. BK=32, BN=256, BM = MFRAG*32 (256 or 128).
// 512 threads = 8 waves (2m x 4n); wave owns (MFRAG/2)*16 rows x 64 cols.
// 4-slot LDS ring: consume tile kt from slot kt&3 while tile kt+2 stages into
// slot (kt+2)&3 via global_load_lds. One s_barrier + counted vmcnt per K-step
// (never vmcnt(0) in the loop). 2-bit XOR chunk swizzle, pre-swizzled source.
template<int MFRAG, bool BF16OUT>
__global__ __launch_bounds__(512, 2) void gemm_ring(
    const u16* __restrict__ A, const u16* __restrict__ B, void* __restrict__ Cv,
    int N, int K, int nbn) {
    constexpr int BM     = MFRAG * 32;
    constexpr int ABYTES = BM * 64;          // BM rows x 32 bf16 (64 B/row)
    constexpr int SLOT   = ABYTES + 16384;   // + B: 256 rows x 64 B
    __shared__ __align__(16) char sm[4 * SLOT];

    const int tid = threadIdx.x;
    const int w = tid >> 6, l = tid & 63;
    const int wm = w >> 2, wn = w & 3;
    const int g = l >> 4, c0 = l & 15;
    const int bid = blockIdx.x;
    const int bm = bid / nbn, bn = bid % nbn;

    // staging: lane l covers LDS row w*16 + (l>>2), chunk l&3 (16 B chunks)
    const int srow   = l >> 2;
    const int schunk = (l & 3) ^ (srow & 3) ^ ((srow >> 2) & 3);
    const u16* As = A + (size_t)(bm * BM  + w*16 + srow) * K + schunk * 8;
    const u16* Bs = B + (size_t)(bn * 256 + w*16 + srow) * K + schunk * 8;

    // read-side swizzled chunk offset (constant per lane)
    const int rswz = ((g ^ (c0 & 3) ^ ((c0 >> 2) & 3)) & 3) * 16;

    f32x4 acc[MFRAG][4] = {};

    auto stage = [&](int st, int ss) {
        char* aB = sm + ss * SLOT;
        char* bB = aB + ABYTES;
        const u16* as = As + (size_t)st * 32;
        const u16* bs = Bs + (size_t)st * 32;
        async_copy16(aB + (w*16) * 64, as);
        if (MFRAG == 8)
            async_copy16(aB + (128 + w*16) * 64, as + (size_t)128 * K);
        async_copy16(bB + (w*16) * 64, bs);
        async_copy16(bB + (128 + w*16) * 64, bs + (size_t)128 * K);
    };

    const int nkt = K >> 5;
    stage(0, 0);
    stage(1, 1);

    for (int kt = 0; kt < nkt; ++kt) {
        const int st = (kt + 2 < nkt) ? kt + 2 : nkt - 1;   // clamped tail restage
        stage(st, (kt + 2) & 3);
        if (MFRAG == 8) asm volatile("s_waitcnt vmcnt(8)" ::: "memory");
        else            asm volatile("s_waitcnt vmcnt(6)" ::: "memory");
        __builtin_amdgcn_s_barrier();
        asm volatile("" ::: "memory");

        const char* aB = sm + (kt & 3) * SLOT;
        const char* bB = aB + ABYTES;
        bf16x8 bfr[4];
#pragma unroll
        for (int n = 0; n < 4; ++n)
            bfr[n] = *(const bf16x8*)(bB + (wn*64 + n*16 + c0) * 64 + rswz);
        bf16x8 afr[MFRAG];
#pragma unroll
        for (int m = 0; m < MFRAG; ++m)
            afr[m] = *(const bf16x8*)(aB + (wm*(BM/2) + m*16 + c0) * 64 + rswz);

        __builtin_amdgcn_s_setprio(1);
#pragma unroll
        for (int m = 0; m < MFRAG; ++m)
#pragma unroll
            for (int n = 0; n < 4; ++n)
                acc[m][n] = __builtin_amdgcn_mfma_f32_16x16x32_bf16(
                    afr[m], bfr[n], acc[m][n], 0, 0, 0);
        __builtin_amdgcn_s_setprio(0);
        asm volatile("" ::: "memory");
    }
    asm volatile("s_waitcnt vmcnt(0)" ::: "memory");  // drain before LDS dealloc

#pragma unroll
    for (int m = 0; m < MFRAG; ++m)
#pragma unroll
        for (int n = 0; n < 4; ++n) {
            const int row = bm*BM + wm*(BM/2) + m*16 + g*4;
            const int col = bn*256 + wn*64 + n*16 + c0;
#pragma unroll
            for (int r = 0; r < 4; ++r) {
                if (BF16OUT)
                    ((u16*)Cv)[(size_t)(row + r) * N + col] = f32_to_bf16bits(acc[m][n][r]);
                else
                    ((float*)Cv)[(size_t)(row + r) * N + col] = acc[m][n][r];
            }
        }
}

// ---------------------------------------------------------------- flash attention
// (unchanged from round 2 — validated)
__global__ __launch_bounds__(256, 2) void attn_kernel(
    const u16* __restrict__ qkv, const u16* __restrict__ vT, u16* __restrict__ outp) {
    __shared__ __align__(16) char lds[65536];
    const int tid = threadIdx.x;
    const int w = tid >> 6, l = tid & 63;
    const int g = l >> 4, c0 = l & 15;
    const int qt = (blockIdx.y < 16) ? blockIdx.x : (15 - (int)blockIdx.x);
    const int h = blockIdx.y;
    const int kvh = h >> 2;
    const int q0g = qt * 128;
    const int qrow0 = q0g + w * 32;

    const int srK = w*4 + g,        scK = c0 ^ srK;
    const int srV = w*8 + (l >> 3), scV = (l & 7) ^ (l >> 3);

#pragma unroll
    for (int i = 0; i < 8; ++i)
        async_copy16(lds + (i*16 + w*4) * 256,
                     qkv + (size_t)(q0g + i*16 + srK) * 6144 + h*128 + scK*8);
    __syncthreads();

#pragma unroll
    for (int i = 0; i < 4; ++i)
        async_copy16(lds + 32768 + (i*16 + w*4) * 256,
                     qkv + (size_t)(i*16 + srK) * 6144 + 4096 + kvh*128 + scK*8);
#pragma unroll
    for (int i = 0; i < 4; ++i)
        async_copy16(lds + 49152 + (i*32 + w*8) * 128,
                     vT + (size_t)(kvh*128 + i*32 + srV) * 2048 + scV*8);

    bf16x8 qf[2][4];
#pragma unroll
    for (int i = 0; i < 2; ++i)
#pragma unroll
        for (int dks = 0; dks < 4; ++dks) {
            const int row = w*32 + i*16 + c0;
            qf[i][dks] = *(const bf16x8*)(lds + row*256 + (((dks*4 + g) ^ c0) * 16));
        }
    __syncthreads();

    f32x4 o[2][8] = {};
    float lsum[2] = {0.f, 0.f};
    const int ntiles = 2*qt + 2;
    const float SC2 = 0.08838834764831845f * 1.4426950408889634f;

    for (int kt = 0; kt < ntiles; ++kt) {
        const int cur = kt & 1;
        const char* kb = lds + (cur ? 0 : 32768);
        const char* vb = lds + (cur ? 16384 : 49152);
        if (kt + 1 < ntiles) {
            char* kbn = lds + ((cur ^ 1) ? 0 : 32768);
            char* vbn = lds + ((cur ^ 1) ? 16384 : 49152);
#pragma unroll
            for (int i = 0; i < 4; ++i)
                async_copy16(kbn + (i*16 + w*4) * 256,
                             qkv + (size_t)((kt+1)*64 + i*16 + srK) * 6144 + 4096 + kvh*128 + scK*8);
#pragma unroll
            for (int i = 0; i < 4; ++i)
                async_copy16(vbn + (i*32 + w*8) * 128,
                             vT + (size_t)(kvh*128 + i*32 + srV) * 2048 + (kt+1)*64 + scV*8);
        }

        if (kt*64 <= qrow0 + 31) {
            f32x4 st[2][4] = {};
            __builtin_amdgcn_s_setprio(1);
#pragma unroll
            for (int dks = 0; dks < 4; ++dks) {
                bf16x8 kf[4];
#pragma unroll
                for (int j = 0; j < 4; ++j) {
                    const int row = j*16 + c0;
                    kf[j] = *(const bf16x8*)(kb + row*256 + (((dks*4 + g) ^ c0) * 16));
                }
#pragma unroll
                for (int i = 0; i < 2; ++i)
#pragma unroll
                    for (int j = 0; j < 4; ++j)
                        st[i][j] = __builtin_amdgcn_mfma_f32_16x16x32_bf16(
                            kf[j], qf[i][dks], st[i][j], 0, 0, 0);
            }
            __builtin_amdgcn_s_setprio(0);

            const bool diag = (kt*64 + 63) > qrow0;
            u32 pk[2][4][2];
#pragma unroll
            for (int i = 0; i < 2; ++i) {
                float rowsum = 0.f;
#pragma unroll
                for (int j = 0; j < 4; ++j) {
#pragma unroll
                    for (int r = 0; r < 4; ++r) {
                        float p = exp2f(st[i][j][r] * SC2);
                        if (diag) {
                            const int kgl = kt*64 + j*16 + g*4 + r;
                            const int qgl = qrow0 + i*16 + c0;
                            if (kgl > qgl) p = 0.f;
                        }
                        st[i][j][r] = p;
                        rowsum += p;
                    }
                    pk[i][j][0] = cvt_pk_bf16(st[i][j][0], st[i][j][1]);
                    pk[i][j][1] = cvt_pk_bf16(st[i][j][2], st[i][j][3]);
                }
                rowsum += __shfl_xor(rowsum, 16);
                rowsum += __shfl_xor(rowsum, 32);
                lsum[i] += rowsum;
            }

#pragma unroll
            for (int dks = 0; dks < 2; ++dks) {
                bf16x8 pf[2];
#pragma unroll
                for (int i = 0; i < 2; ++i) {
                    union { u32 u[4]; bf16x8 v; } pu;
                    pu.u[0] = pk[i][2*dks][0];   pu.u[1] = pk[i][2*dks][1];
                    pu.u[2] = pk[i][2*dks+1][0]; pu.u[3] = pk[i][2*dks+1][1];
                    pf[i] = pu.v;
                }
                __builtin_amdgcn_s_setprio(1);
#pragma unroll
                for (int dj = 0; dj < 8; ++dj) {
                    const int row = dj*16 + c0;
                    const int cg0 = (4*dks + (g >> 1)) ^ (row & 7);
                    const int cg1 = (4*dks + (g >> 1) + 2) ^ (row & 7);
                    union { struct { bf16x4 lo, hi; } p; bf16x8 v; } vu;
                    vu.p.lo = *(const bf16x4*)(vb + row*128 + cg0*16 + 8*(g & 1));
                    vu.p.hi = *(const bf16x4*)(vb + row*128 + cg1*16 + 8*(g & 1));
#pragma unroll
                    for (int i = 0; i < 2; ++i)
                        o[i][dj] = __builtin_amdgcn_mfma_f32_16x16x32_bf16(
                            vu.v, pf[i], o[i][dj], 0, 0, 0);
                }
                __builtin_amdgcn_s_setprio(0);
            }
        }
        __syncthreads();
    }

#pragma unroll
    for (int i = 0; i < 2; ++i) {
        const float rcp = 1.0f / lsum[i];
        const int qg = qrow0 + i*16 + c0;
#pragma unroll
        for (int dj = 0; dj < 8; ++dj) {
            u16x4 ov = { f32_to_bf16bits(o[i][dj][0] * rcp),
                         f32_to_bf16bits(o[i][dj][1] * rcp),
                         f32_to_bf16bits(o[i][dj][2] * rcp),
                         f32_to_bf16bits(o[i][dj][3] * rcp) };
            *(u16x4*)(outp + (size_t)qg * 4096 + h*128 + dj*16 + g*4) = ov;
        }
    }
}

// ---------------------------------------------------------------- launcher
extern "C" void kernel_launch(void* const* d_in, const int* in_sizes, int n_in,
                              void* d_out, int out_size, void* d_ws, size_t ws_size,
                              hipStream_t stream) {
    const float* x    = (const float*)d_in[0];
    const float* wq   = (const float*)d_in[1];
    const float* wk   = (const float*)d_in[2];
    const float* wv   = (const float*)d_in[3];
    const float* wo   = (const float*)d_in[4];
    const float* cosp = (const float*)d_in[5];
    const float* sinp = (const float*)d_in[6];
    // d_in[7] = mask — causality applied analytically in attn_kernel.

    char* ws = (char*)d_ws;
    u16* xb    = (u16*)(ws);                       //  16.8 MB  x bf16 (2048x4096)
    u16* wqkvT = (u16*)(ws + 16777216);            //  50.3 MB  [wq|wk|wv]^T (6144x4096)
    u16* woT   = (u16*)(ws + 67108864);            //  33.6 MB  wo^T (4096x4096)
    u16* qkv   = (u16*)(ws + 100663296);           //  25.2 MB  qkv (2048x6144)
    u16* vTb   = (u16*)(ws + 125829120);           //   4.2 MB  v^T (1024x2048)
    u16* attn  = (u16*)(ws + 130023424);           //  16.8 MB  attn out (2048x4096)

    dim3 tb(32, 8);
    convert_f32_bf16<<<8192, 256, 0, stream>>>(x, xb, 2097152);
    transpose_wT<<<dim3(32, 128), tb, 0, stream>>>(wq, wqkvT, 4096, 4096);
    transpose_wT<<<dim3(8, 128),  tb, 0, stream>>>(wk, wqkvT + (size_t)4096*4096, 1024, 4096);
    transpose_wT<<<dim3(8, 128),  tb, 0, stream>>>(wv, wqkvT + (size_t)5120*4096, 1024, 4096);
    transpose_wT<<<dim3(32, 128), tb, 0, stream>>>(wo, woT, 4096, 4096);

    gemm_ring<8, true><<<192, 512, 0, stream>>>(xb, wqkvT, qkv, 6144, 4096, 24);
    rope_kernel<<<dim3(2048, 10), 256, 0, stream>>>((u32*)qkv, cosp, sinp);
    transpose_v<<<dim3(64, 32), tb, 0, stream>>>(qkv, vTb);
    attn_kernel<<<dim3(16, 32), 256, 0, stream>>>(qkv, vTb, attn);
    gemm_ring<4, false><<<256, 512, 0, stream>>>(attn, woT, d_out, 4096, 4096, 16);
}

// Round 4
// 315.405 us; speedup vs baseline: 1.0473x; 1.0473x over previous
//
#include <hip/hip_runtime.h>
#include <hip/hip_bf16.h>

typedef unsigned short u16;
typedef unsigned int   u32;
typedef __attribute__((ext_vector_type(8))) short bf16x8;
typedef __attribute__((ext_vector_type(4))) short bf16x4;
typedef __attribute__((ext_vector_type(4))) float f32x4;
typedef __attribute__((ext_vector_type(4))) unsigned short u16x4;

__device__ __forceinline__ u16 f32_to_bf16bits(float f) {
    u32 x = __float_as_uint(f);
    u32 r = (x + 0x7fffu + ((x >> 16) & 1u)) >> 16;   // RNE
    return (u16)r;
}
__device__ __forceinline__ float bf16bits_to_f32(u16 u) {
    return __uint_as_float(((u32)u) << 16);
}
__device__ __forceinline__ u32 cvt_pk_bf16(float lo, float hi) {
    u32 r;
    asm("v_cvt_pk_bf16_f32 %0, %1, %2" : "=v"(r) : "v"(lo), "v"(hi));
    return r;
}

// async global->LDS, 16B per lane. LDS dest is wave-uniform base + lane*16.
__device__ __forceinline__ void async_copy16(void* lds, const void* g) {
    __builtin_amdgcn_global_load_lds(
        (__attribute__((address_space(1))) void*)(g),
        (__attribute__((address_space(3))) void*)(lds), 16, 0, 0);
}

// ---------------------------------------------------------------- convert x
__global__ void convert_f32_bf16(const float* __restrict__ src, u16* __restrict__ dst, int n4) {
    const int i = blockIdx.x * 256 + threadIdx.x;
    if (i >= n4) return;
    const float4 v = ((const float4*)src)[i];
    u16x4 o = { f32_to_bf16bits(v.x), f32_to_bf16bits(v.y),
                f32_to_bf16bits(v.z), f32_to_bf16bits(v.w) };
    ((u16x4*)dst)[i] = o;
}

// ------------------------------------------- weight transpose fp32(K,N)->bf16(N,K)
__global__ void transpose_wT(const float* __restrict__ src, u16* __restrict__ dst,
                             int N, int dstStride) {
    __shared__ float tile[32][129];
    const int n0 = blockIdx.x * 128, k0 = blockIdx.y * 32;
    const int tx = threadIdx.x, ty = threadIdx.y;      // (32, 8)
#pragma unroll
    for (int j = 0; j < 4; ++j)
#pragma unroll
        for (int i = 0; i < 4; ++i)
            tile[ty + 8*j][tx + 32*i] = src[(size_t)(k0 + ty + 8*j) * N + n0 + tx + 32*i];
    __syncthreads();
    const int tid = ty * 32 + tx;
    const int c = tid & 15, nl0 = tid >> 4;
#pragma unroll
    for (int s = 0; s < 8; ++s) {
        const int nl = nl0 + s * 16;
        const u32 pk = (u32)f32_to_bf16bits(tile[2*c][nl])
                     | ((u32)f32_to_bf16bits(tile[2*c + 1][nl]) << 16);
        *(u32*)&dst[(size_t)(n0 + nl) * dstStride + k0 + 2*c] = pk;
    }
}

// ------------------------------------------- V transpose bf16 (s,dcol)->(dcol,s)
__global__ void transpose_v(const u16* __restrict__ qkv, u16* __restrict__ vT) {
    __shared__ u16 tile[32][34];
    const int s0 = blockIdx.x * 32, n0 = blockIdx.y * 32;
    const int tx = threadIdx.x, ty = threadIdx.y;
#pragma unroll
    for (int i = 0; i < 4; ++i)
        tile[ty + i*8][tx] = qkv[(size_t)(s0 + ty + i*8) * 6144 + 5120 + n0 + tx];
    __syncthreads();
#pragma unroll
    for (int i = 0; i < 4; ++i)
        vT[(size_t)(n0 + ty + i*8) * 2048 + s0 + tx] = tile[tx][ty + i*8];
}

// ---------------------------------------------------------------- RoPE in place
__global__ void rope_kernel(u32* __restrict__ qkv, const float* __restrict__ cosp,
                            const float* __restrict__ sinp) {
    const int s = blockIdx.x;
    const int h = blockIdx.y * 4 + (threadIdx.x >> 6);
    const int p = threadIdx.x & 63;
    const size_t off = ((size_t)s * 6144 + h * 128) >> 1;
    const u32 packed = qkv[off + p];
    const float c  = cosp[s*64 + p], sn = sinp[s*64 + p];
    const float t1 = bf16bits_to_f32((u16)(packed & 0xffffu));
    const float t2 = bf16bits_to_f32((u16)(packed >> 16));
    const float o1 = t1 * c - t2 * sn;
    const float o2 = t1 * sn + t2 * c;
    qkv[off + p] = (u32)f32_to_bf16bits(o1) | ((u32)f32_to_bf16bits(o2) << 16);
}

// ---------------------------------------------------------------- 8-phase GEMM
// C[M,N] = A[M,K] * B[N,K]^T.  BK=64, BN=256, BM=MREP*32.  512 thr = 8 waves
// (2m x 4n).  LDS: A[d][h] halves of (BM/2)x64 bf16, B[d][h] halves of 128x64;
// double-buffered (d = ktile&1).  Per phase: ds-read one quadrant's frags ->
// stage one half-tile (global_load_lds) -> s_barrier -> lgkmcnt(0) ->
// setprio(1) -> 2*(MREP/2)*2 MFMA -> setprio(0) -> s_barrier.  Counted
// s_waitcnt vmcnt(4) only at phases 3 and 7 (loads stay in flight across
// barriers).  BK=64 rows (128B) + chunk-XOR swizzle = conflict-free reads.
#define RD_A(d, mh) do { _Pragma("unroll")                                    \
    for (int mi = 0; mi < MREP/2; ++mi) {                                     \
        const char* ab = sm + ((d)*2 + wm)*HALF_A                             \
                       + (((mh)*(MREP/2)+mi)*16 + c0)*128;                    \
        af[mi][0] = *(const bf16x8*)(ab + ((g ^ (c0&7)) * 16));               \
        af[mi][1] = *(const bf16x8*)(ab + (((4+g) ^ (c0&7)) * 16));           \
    } } while (0)

#define RD_B(d, nh) do { _Pragma("unroll")                                    \
    for (int ni = 0; ni < 2; ++ni) {                                          \
        const char* bb = sm + BOFF + ((d)*2 + bh)*16384                       \
                       + ((wn&1)*64 + ((nh)*2+ni)*16 + c0)*128;               \
        bf[(nh)*2+ni][0] = *(const bf16x8*)(bb + ((g ^ (c0&7)) * 16));        \
        bf[(nh)*2+ni][1] = *(const bf16x8*)(bb + (((4+g) ^ (c0&7)) * 16));    \
    } } while (0)

#define MFMA_PH(mh, nh) do {                                                  \
    __builtin_amdgcn_s_barrier();                                             \
    asm volatile("s_waitcnt lgkmcnt(0)" ::: "memory");                        \
    __builtin_amdgcn_sched_barrier(0);                                        \
    __builtin_amdgcn_s_setprio(1);                                            \
    _Pragma("unroll") for (int dk = 0; dk < 2; ++dk)                          \
    _Pragma("unroll") for (int mi = 0; mi < MREP/2; ++mi)                     \
    _Pragma("unroll") for (int ni = 0; ni < 2; ++ni)                          \
        acc[(mh)*(MREP/2)+mi][(nh)*2+ni] =                                    \
            __builtin_amdgcn_mfma_f32_16x16x32_bf16(                          \
                af[mi][dk], bf[(nh)*2+ni][dk],                                \
                acc[(mh)*(MREP/2)+mi][(nh)*2+ni], 0, 0, 0);                   \
    __builtin_amdgcn_s_setprio(0); } while (0)

#define ENDBAR() __builtin_amdgcn_s_barrier()
#define VMC4()   asm volatile("s_waitcnt vmcnt(4)" ::: "memory")

template<int MREP, bool BF16OUT>
__global__ __launch_bounds__(512, 2) void gemm8p(
    const u16* __restrict__ A, const u16* __restrict__ B, void* __restrict__ Cv,
    const int N, const int K, const int nbn) {
    constexpr int BM     = MREP * 32;
    constexpr int HALF_A = (BM/2) * 128;   // bytes per A half-tile
    constexpr int BOFF   = 4 * HALF_A;     // A[2][2] then B[2][2]
    __shared__ __align__(16) char sm[BOFF + 65536];

    const int tid = threadIdx.x;
    const int w = tid >> 6, l = tid & 63;
    const int wm = w >> 2, wn = w & 3, bh = wn >> 1;
    const int g = l >> 4, c0 = l & 15;
    const int bm = blockIdx.x / nbn, bn = blockIdx.x % nbn;

    const int srow   = w*8 + (l >> 3);          // staging row (within 64-row round)
    const int schunk = (l & 7) ^ (l >> 3);      // pre-swizzled source chunk
    const u16* Abase = A + (size_t)(bm*BM  + srow) * K + schunk*8;
    const u16* Bbase = B + (size_t)(bn*256 + srow) * K + schunk*8;

    f32x4 acc[MREP][4] = {};
    bf16x8 af[MREP/2][2], bf[4][2];

    auto stageA = [&](int kt, int d, int h) {
        char* dst = sm + (d*2 + h) * HALF_A + (w*8) * 128;
        const u16* src = Abase + (size_t)h*(BM/2)*K + kt*64;
#pragma unroll
        for (int r = 0; r < MREP/4; ++r)
            async_copy16(dst + r*64*128, src + (size_t)r*64*K);
    };
    auto stageB = [&](int kt, int d, int h) {
        char* dst = sm + BOFF + (d*2 + h) * 16384 + (w*8) * 128;
        const u16* src = Bbase + (size_t)h*128*K + kt*64;
#pragma unroll
        for (int r = 0; r < 2; ++r)
            async_copy16(dst + r*64*128, src + (size_t)r*64*K);
    };

    const int nkt = K >> 6;    // K-tiles of 64 (even, >= 2)

    // prologue: ktile0 fully + ktile1's B halves; retire ktile0, keep B1 in flight
    stageB(0, 0, 0); stageB(0, 0, 1);
    stageA(0, 0, 0); stageA(0, 0, 1);
    stageB(1, 1, 0); stageB(1, 1, 1);
    VMC4();
    __builtin_amdgcn_s_barrier();

    for (int t = 0; t < nkt; t += 2) {
        const int tb = t + 1, tc = t + 2, td = t + 3;
        // p0: q(0,0) of ktile t (buf0); stage A[1][0] <- ktile t+1
        RD_A(0, 0); RD_B(0, 0); stageA(tb, 1, 0);
        MFMA_PH(0, 0); ENDBAR();
        // p1: q(0,1); stage A[1][1] <- ktile t+1
        RD_B(0, 1); stageA(tb, 1, 1);
        MFMA_PH(0, 1); ENDBAR();
        // p2: q(1,0); stage B[0][0] <- ktile t+2 (B[0] reads done by p1-end)
        RD_A(0, 1); if (tc < nkt) stageB(tc, 0, 0);
        MFMA_PH(1, 0); ENDBAR();
        // p3: q(1,1); stage B[0][1] <- ktile t+2; vmcnt(4) retires A[1]/B[1]
        if (tc < nkt) stageB(tc, 0, 1);
        MFMA_PH(1, 1); VMC4(); ENDBAR();
        // p4: q(0,0) of ktile t+1 (buf1); stage A[0][0] <- ktile t+2
        RD_A(1, 0); RD_B(1, 0); if (tc < nkt) stageA(tc, 0, 0);
        MFMA_PH(0, 0); ENDBAR();
        // p5: q(0,1); stage A[0][1] <- ktile t+2
        RD_B(1, 1); if (tc < nkt) stageA(tc, 0, 1);
        MFMA_PH(0, 1); ENDBAR();
        // p6: q(1,0); stage B[1][0] <- ktile t+3 (B[1] reads done by p5-end)
        RD_A(1, 1); if (td < nkt) stageB(td, 1, 0);
        MFMA_PH(1, 0); ENDBAR();
        // p7: q(1,1); stage B[1][1] <- ktile t+3; vmcnt(4) retires ktile t+2
        if (td < nkt) stageB(td, 1, 1);
        MFMA_PH(1, 1); VMC4(); ENDBAR();
    }
    asm volatile("s_waitcnt vmcnt(0)" ::: "memory");  // drain before LDS dealloc

#pragma unroll
    for (int m = 0; m < MREP; ++m)
#pragma unroll
        for (int n = 0; n < 4; ++n) {
            const int row = bm*BM + wm*(BM/2) + m*16 + g*4;
            const int col = bn*256 + wn*64 + n*16 + c0;
#pragma unroll
            for (int r = 0; r < 4; ++r) {
                if (BF16OUT)
                    ((u16*)Cv)[(size_t)(row + r) * N + col] = f32_to_bf16bits(acc[m][n][r]);
                else
                    ((float*)Cv)[(size_t)(row + r) * N + col] = acc[m][n][r];
            }
        }
}
#undef RD_A
#undef RD_B
#undef MFMA_PH
#undef ENDBAR
#undef VMC4

// ---------------------------------------------------------------- flash attention
// (unchanged — validated in rounds 2-3)
__global__ __launch_bounds__(256, 2) void attn_kernel(
    const u16* __restrict__ qkv, const u16* __restrict__ vT, u16* __restrict__ outp) {
    __shared__ __align__(16) char lds[65536];
    const int tid = threadIdx.x;
    const int w = tid >> 6, l = tid & 63;
    const int g = l >> 4, c0 = l & 15;
    const int qt = (blockIdx.y < 16) ? blockIdx.x : (15 - (int)blockIdx.x);
    const int h = blockIdx.y;
    const int kvh = h >> 2;
    const int q0g = qt * 128;
    const int qrow0 = q0g + w * 32;

    const int srK = w*4 + g,        scK = c0 ^ srK;
    const int srV = w*8 + (l >> 3), scV = (l & 7) ^ (l >> 3);

#pragma unroll
    for (int i = 0; i < 8; ++i)
        async_copy16(lds + (i*16 + w*4) * 256,
                     qkv + (size_t)(q0g + i*16 + srK) * 6144 + h*128 + scK*8);
    __syncthreads();

#pragma unroll
    for (int i = 0; i < 4; ++i)
        async_copy16(lds + 32768 + (i*16 + w*4) * 256,
                     qkv + (size_t)(i*16 + srK) * 6144 + 4096 + kvh*128 + scK*8);
#pragma unroll
    for (int i = 0; i < 4; ++i)
        async_copy16(lds + 49152 + (i*32 + w*8) * 128,
                     vT + (size_t)(kvh*128 + i*32 + srV) * 2048 + scV*8);

    bf16x8 qf[2][4];
#pragma unroll
    for (int i = 0; i < 2; ++i)
#pragma unroll
        for (int dks = 0; dks < 4; ++dks) {
            const int row = w*32 + i*16 + c0;
            qf[i][dks] = *(const bf16x8*)(lds + row*256 + (((dks*4 + g) ^ c0) * 16));
        }
    __syncthreads();

    f32x4 o[2][8] = {};
    float lsum[2] = {0.f, 0.f};
    const int ntiles = 2*qt + 2;
    const float SC2 = 0.08838834764831845f * 1.4426950408889634f;

    for (int kt = 0; kt < ntiles; ++kt) {
        const int cur = kt & 1;
        const char* kb = lds + (cur ? 0 : 32768);
        const char* vb = lds + (cur ? 16384 : 49152);
        if (kt + 1 < ntiles) {
            char* kbn = lds + ((cur ^ 1) ? 0 : 32768);
            char* vbn = lds + ((cur ^ 1) ? 16384 : 49152);
#pragma unroll
            for (int i = 0; i < 4; ++i)
                async_copy16(kbn + (i*16 + w*4) * 256,
                             qkv + (size_t)((kt+1)*64 + i*16 + srK) * 6144 + 4096 + kvh*128 + scK*8);
#pragma unroll
            for (int i = 0; i < 4; ++i)
                async_copy16(vbn + (i*32 + w*8) * 128,
                             vT + (size_t)(kvh*128 + i*32 + srV) * 2048 + (kt+1)*64 + scV*8);
        }

        if (kt*64 <= qrow0 + 31) {
            f32x4 st[2][4] = {};
            __builtin_amdgcn_s_setprio(1);
#pragma unroll
            for (int dks = 0; dks < 4; ++dks) {
                bf16x8 kf[4];
#pragma unroll
                for (int j = 0; j < 4; ++j) {
                    const int row = j*16 + c0;
                    kf[j] = *(const bf16x8*)(kb + row*256 + (((dks*4 + g) ^ c0) * 16));
                }
#pragma unroll
                for (int i = 0; i < 2; ++i)
#pragma unroll
                    for (int j = 0; j < 4; ++j)
                        st[i][j] = __builtin_amdgcn_mfma_f32_16x16x32_bf16(
                            kf[j], qf[i][dks], st[i][j], 0, 0, 0);
            }
            __builtin_amdgcn_s_setprio(0);

            const bool diag = (kt*64 + 63) > qrow0;
            u32 pk[2][4][2];
#pragma unroll
            for (int i = 0; i < 2; ++i) {
                float rowsum = 0.f;
#pragma unroll
                for (int j = 0; j < 4; ++j) {
#pragma unroll
                    for (int r = 0; r < 4; ++r) {
                        float p = exp2f(st[i][j][r] * SC2);
                        if (diag) {
                            const int kgl = kt*64 + j*16 + g*4 + r;
                            const int qgl = qrow0 + i*16 + c0;
                            if (kgl > qgl) p = 0.f;
                        }
                        st[i][j][r] = p;
                        rowsum += p;
                    }
                    pk[i][j][0] = cvt_pk_bf16(st[i][j][0], st[i][j][1]);
                    pk[i][j][1] = cvt_pk_bf16(st[i][j][2], st[i][j][3]);
                }
                rowsum += __shfl_xor(rowsum, 16);
                rowsum += __shfl_xor(rowsum, 32);
                lsum[i] += rowsum;
            }

#pragma unroll
            for (int dks = 0; dks < 2; ++dks) {
                bf16x8 pf[2];
#pragma unroll
                for (int i = 0; i < 2; ++i) {
                    union { u32 u[4]; bf16x8 v; } pu;
                    pu.u[0] = pk[i][2*dks][0];   pu.u[1] = pk[i][2*dks][1];
                    pu.u[2] = pk[i][2*dks+1][0]; pu.u[3] = pk[i][2*dks+1][1];
                    pf[i] = pu.v;
                }
                __builtin_amdgcn_s_setprio(1);
#pragma unroll
                for (int dj = 0; dj < 8; ++dj) {
                    const int row = dj*16 + c0;
                    const int cg0 = (4*dks + (g >> 1)) ^ (row & 7);
                    const int cg1 = (4*dks + (g >> 1) + 2) ^ (row & 7);
                    union { struct { bf16x4 lo, hi; } p; bf16x8 v; } vu;
                    vu.p.lo = *(const bf16x4*)(vb + row*128 + cg0*16 + 8*(g & 1));
                    vu.p.hi = *(const bf16x4*)(vb + row*128 + cg1*16 + 8*(g & 1));
#pragma unroll
                    for (int i = 0; i < 2; ++i)
                        o[i][dj] = __builtin_amdgcn_mfma_f32_16x16x32_bf16(
                            vu.v, pf[i], o[i][dj], 0, 0, 0);
                }
                __builtin_amdgcn_s_setprio(0);
            }
        }
        __syncthreads();
    }

#pragma unroll
    for (int i = 0; i < 2; ++i) {
        const float rcp = 1.0f / lsum[i];
        const int qg = qrow0 + i*16 + c0;
#pragma unroll
        for (int dj = 0; dj < 8; ++dj) {
            u16x4 ov = { f32_to_bf16bits(o[i][dj][0] * rcp),
                         f32_to_bf16bits(o[i][dj][1] * rcp),
                         f32_to_bf16bits(o[i][dj][2] * rcp),
                         f32_to_bf16bits(o[i][dj][3] * rcp) };
            *(u16x4*)(outp + (size_t)qg * 4096 + h*128 + dj*16 + g*4) = ov;
        }
    }
}

// ---------------------------------------------------------------- launcher
extern "C" void kernel_launch(void* const* d_in, const int* in_sizes, int n_in,
                              void* d_out, int out_size, void* d_ws, size_t ws_size,
                              hipStream_t stream) {
    const float* x    = (const float*)d_in[0];
    const float* wq   = (const float*)d_in[1];
    const float* wk   = (const float*)d_in[2];
    const float* wv   = (const float*)d_in[3];
    const float* wo   = (const float*)d_in[4];
    const float* cosp = (const float*)d_in[5];
    const float* sinp = (const float*)d_in[6];
    // d_in[7] = mask — causality applied analytically in attn_kernel.

    char* ws = (char*)d_ws;
    u16* xb    = (u16*)(ws);                       //  16.8 MB  x bf16 (2048x4096)
    u16* wqkvT = (u16*)(ws + 16777216);            //  50.3 MB  [wq|wk|wv]^T (6144x4096)
    u16* woT   = (u16*)(ws + 67108864);            //  33.6 MB  wo^T (4096x4096)
    u16* qkv   = (u16*)(ws + 100663296);           //  25.2 MB  qkv (2048x6144)
    u16* vTb   = (u16*)(ws + 125829120);           //   4.2 MB  v^T (1024x2048)
    u16* attn  = (u16*)(ws + 130023424);           //  16.8 MB  attn out (2048x4096)

    dim3 tb(32, 8);
    convert_f32_bf16<<<8192, 256, 0, stream>>>(x, xb, 2097152);
    transpose_wT<<<dim3(32, 128), tb, 0, stream>>>(wq, wqkvT, 4096, 4096);
    transpose_wT<<<dim3(8, 128),  tb, 0, stream>>>(wk, wqkvT + (size_t)4096*4096, 1024, 4096);
    transpose_wT<<<dim3(8, 128),  tb, 0, stream>>>(wv, wqkvT + (size_t)5120*4096, 1024, 4096);
    transpose_wT<<<dim3(32, 128), tb, 0, stream>>>(wo, woT, 4096, 4096);

    gemm8p<8, true><<<192, 512, 0, stream>>>(xb, wqkvT, qkv, 6144, 4096, 24);
    rope_kernel<<<dim3(2048, 10), 256, 0, stream>>>((u32*)qkv, cosp, sinp);
    transpose_v<<<dim3(64, 32), tb, 0, stream>>>(qkv, vTb);
    attn_kernel<<<dim3(16, 32), 256, 0, stream>>>(qkv, vTb, attn);
    gemm8p<4, false><<<256, 512, 0, stream>>>(attn, woT, d_out, 4096, 4096, 16);
}